// Round 1
// baseline (294.427 us; speedup 1.0000x reference)
//
#include <hip/hip_runtime.h>

// Problem constants
#define BATCH 4
#define SEQ   4096
#define DIM   256   // DIN == DK == 256

typedef float          f32x4 __attribute__((ext_vector_type(4)));
typedef unsigned short u16x8 __attribute__((ext_vector_type(8)));
typedef unsigned short u16x4 __attribute__((ext_vector_type(4)));
typedef __bf16         bf16x8 __attribute__((ext_vector_type(8)));

__device__ __forceinline__ unsigned short f2bf(float f) {
  unsigned u = __builtin_bit_cast(unsigned, f);
  u += 0x7fffu + ((u >> 16) & 1u);          // RNE
  return (unsigned short)(u >> 16);
}
__device__ __forceinline__ bf16x8 as_bf(u16x8 v) { return __builtin_bit_cast(bf16x8, v); }

// ---------------------------------------------------------------------------
// Kernel 1: W[k][n] fp32  ->  Wt[n][k] bf16   (3 matrices of 256x256)
// ---------------------------------------------------------------------------
__global__ void wtrans_kernel(const float* __restrict__ Wq,
                              const float* __restrict__ Wk,
                              const float* __restrict__ Wv,
                              unsigned short* __restrict__ Wt) {
  const int mat = blockIdx.y;           // 0=Q 1=K 2=V
  const int n   = blockIdx.x;           // 0..255
  const int k   = threadIdx.x;          // 0..255
  const float* W = (mat == 0) ? Wq : (mat == 1) ? Wk : Wv;
  Wt[(size_t)mat * 65536 + n * 256 + k] = f2bf(W[k * 256 + n]);
}

// ---------------------------------------------------------------------------
// Kernel 2: projections.  C[16384,256] = A @ W + b  (MFMA bf16, fp32 acc)
//  mat 0: Q = (conv_global@Wq + bq) * (1/16)  -> Qb  [m][n] bf16
//  mat 1: K =  conv_local @Wk + bk            -> Kb  [m][n] bf16
//  mat 2: V =  conv_local @Wv + bv            -> Vt  [b][d][kv] bf16 (transposed)
// block 256 thr = 4 waves (2x2), tile 128x128, BK=64
// ---------------------------------------------------------------------------
__global__ __launch_bounds__(256) void proj_kernel(
    const float* __restrict__ conv_global, const float* __restrict__ conv_local,
    const unsigned short* __restrict__ Wt,
    const float* __restrict__ bq, const float* __restrict__ bk, const float* __restrict__ bv,
    unsigned short* __restrict__ Qb, unsigned short* __restrict__ Kb,
    unsigned short* __restrict__ Vt_out) {
  // smem[0] = A tile [128][64+8], smem[1] = Wt tile [128][64+8]; epilogue reuses
  // the whole 36864 B as Ct[128][136] for the V transpose.
  __shared__ __align__(16) unsigned short smem[2][128][72];

  const int mat = blockIdx.z;
  const int m0  = blockIdx.y * 128;
  const int n0  = blockIdx.x * 128;
  const float* A            = (mat == 0) ? conv_global : conv_local;
  const unsigned short* Wtm = Wt + (size_t)mat * 65536;
  const float* bias         = (mat == 0) ? bq : (mat == 1) ? bk : bv;

  const int tid  = threadIdx.x;
  const int wid  = tid >> 6, lane = tid & 63;
  const int g    = lane >> 4, l16 = lane & 15;
  const int wy   = wid >> 1, wx = wid & 1;

  f32x4 acc[4][4];
#pragma unroll
  for (int i = 0; i < 4; ++i)
#pragma unroll
    for (int j = 0; j < 4; ++j) acc[i][j] = f32x4{0.f, 0.f, 0.f, 0.f};

  for (int kk = 0; kk < 4; ++kk) {
    const int k0 = kk * 64;
    __syncthreads();
    // stage A tile: 128x64 fp32 -> bf16, 2048 float4 chunks, 8/thread
#pragma unroll
    for (int i = 0; i < 8; ++i) {
      int id = i * 256 + tid;
      int row = id >> 4, c4 = id & 15;
      f32x4 v = *(const f32x4*)(A + (size_t)(m0 + row) * 256 + k0 + c4 * 4);
      u16x4 w;
      w[0] = f2bf(v[0]); w[1] = f2bf(v[1]); w[2] = f2bf(v[2]); w[3] = f2bf(v[3]);
      *(u16x4*)(&smem[0][row][c4 * 4]) = w;
    }
    // stage Wt tile: 128 rows(n) x 64 cols(k) bf16, 1024 chunks, 4/thread
#pragma unroll
    for (int i = 0; i < 4; ++i) {
      int id = i * 256 + tid;
      int row = id >> 3, cc = id & 7;
      u16x8 v = *(const u16x8*)(Wtm + (size_t)(n0 + row) * 256 + k0 + cc * 8);
      *(u16x8*)(&smem[1][row][cc * 8]) = v;
    }
    __syncthreads();
#pragma unroll
    for (int ks = 0; ks < 2; ++ks) {
      u16x8 af[4], bf[4];
#pragma unroll
      for (int mt = 0; mt < 4; ++mt)
        af[mt] = *(const u16x8*)(&smem[0][wy * 64 + mt * 16 + l16][ks * 32 + g * 8]);
#pragma unroll
      for (int nt = 0; nt < 4; ++nt)
        bf[nt] = *(const u16x8*)(&smem[1][wx * 64 + nt * 16 + l16][ks * 32 + g * 8]);
#pragma unroll
      for (int mt = 0; mt < 4; ++mt)
#pragma unroll
        for (int nt = 0; nt < 4; ++nt)
          acc[mt][nt] = __builtin_amdgcn_mfma_f32_16x16x32_bf16(
              as_bf(af[mt]), as_bf(bf[nt]), acc[mt][nt], 0, 0, 0);
    }
  }

  if (mat < 2) {
    unsigned short* Cout = (mat == 0) ? Qb : Kb;
    const float scale = (mat == 0) ? 0.0625f : 1.0f;   // fold 1/sqrt(DK) into Q
#pragma unroll
    for (int nt = 0; nt < 4; ++nt) {
      const int ng = n0 + wx * 64 + nt * 16 + l16;
      const float bv4 = bias[ng];
#pragma unroll
      for (int mt = 0; mt < 4; ++mt)
#pragma unroll
        for (int r = 0; r < 4; ++r) {
          int mg = m0 + wy * 64 + mt * 16 + g * 4 + r;
          Cout[(size_t)mg * 256 + ng] = f2bf((acc[mt][nt][r] + bv4) * scale);
        }
    }
  } else {
    // V: transpose via LDS so Vt[b][d][kv] stores are coalesced b128
    __syncthreads();
    unsigned short* Ct = &smem[0][0][0];   // [128 n][136 m] = 34816 B
#pragma unroll
    for (int nt = 0; nt < 4; ++nt) {
      const int nl = wx * 64 + nt * 16 + l16;
      const float bv4 = bias[n0 + nl];
#pragma unroll
      for (int mt = 0; mt < 4; ++mt)
#pragma unroll
        for (int r = 0; r < 4; ++r) {
          int ml = wy * 64 + mt * 16 + g * 4 + r;
          Ct[nl * 136 + ml] = f2bf(acc[mt][nt][r] + bv4);
        }
    }
    __syncthreads();
    const int bb = m0 >> 12;          // batch (tiles never straddle batches)
    const int kvb = m0 & 4095;
#pragma unroll
    for (int i = 0; i < 8; ++i) {
      int id = i * 256 + tid;
      int row = id >> 4, cc = id & 15;        // 128 rows(n) x 16 chunks
      u16x8 v = *(const u16x8*)(&Ct[row * 136 + cc * 8]);
      *(u16x8*)(Vt_out + (size_t)bb * 1048576 + (size_t)(n0 + row) * 4096 + kvb + cc * 8) = v;
    }
  }
}

// ---------------------------------------------------------------------------
// Kernel 3: flash attention.  grid (SQ/64, B), block 256 = 4 waves x 16 q-rows
// ---------------------------------------------------------------------------
__global__ __launch_bounds__(256) void attn_kernel(
    const unsigned short* __restrict__ Qb, const unsigned short* __restrict__ Kb,
    const unsigned short* __restrict__ Vt, float* __restrict__ out) {
  __shared__ __align__(16) unsigned short K_lds[64][264];   // [kv][d], pad 8
  __shared__ __align__(16) unsigned short V_lds[256][72];   // [d][kv], pad 8
  __shared__ __align__(16) unsigned short P_lds[4][16][72]; // per-wave P relayout

  const int tid = threadIdx.x;
  const int wid = tid >> 6, lane = tid & 63;
  const int g = lane >> 4, l16 = lane & 15;
  const int b = blockIdx.y, q0 = blockIdx.x * 64;

  // Q A-fragments for 16 rows x 256 d, entirely in registers
  u16x8 qf[8];
  {
    const unsigned short* qbase =
        Qb + ((size_t)(b * SEQ + q0 + wid * 16 + l16)) * 256 + g * 8;
#pragma unroll
    for (int f = 0; f < 8; ++f) qf[f] = *(const u16x8*)(qbase + f * 32);
  }

  f32x4 Oacc[16];
#pragma unroll
  for (int i = 0; i < 16; ++i) Oacc[i] = f32x4{0.f, 0.f, 0.f, 0.f};
  float m_i[4], l_i[4];
#pragma unroll
  for (int r = 0; r < 4; ++r) { m_i[r] = -1e30f; l_i[r] = 0.f; }

  const unsigned short* KbB = Kb + (size_t)b * SEQ * 256;
  const unsigned short* VtB = Vt + (size_t)b * 256 * SEQ;

  for (int kv0 = 0; kv0 < SEQ; kv0 += 64) {
    __syncthreads();
    // stage K tile 64x256 (32 KB): 2048 16B chunks, 8/thread
#pragma unroll
    for (int i = 0; i < 8; ++i) {
      int id = i * 256 + tid;
      int row = id >> 5, cc = id & 31;
      u16x8 v = *(const u16x8*)(KbB + (size_t)(kv0 + row) * 256 + cc * 8);
      *(u16x8*)(&K_lds[row][cc * 8]) = v;
    }
    // stage V tile 256x64 (32 KB) from transposed Vt
#pragma unroll
    for (int i = 0; i < 8; ++i) {
      int id = i * 256 + tid;
      int row = id >> 3, cc = id & 7;
      u16x8 v = *(const u16x8*)(VtB + (size_t)row * SEQ + kv0 + cc * 8);
      *(u16x8*)(&V_lds[row][cc * 8]) = v;
    }
    __syncthreads();

    // S = Q K^T (scale already folded into Q)
    f32x4 s[4];
#pragma unroll
    for (int nt = 0; nt < 4; ++nt) s[nt] = f32x4{0.f, 0.f, 0.f, 0.f};
#pragma unroll
    for (int ks = 0; ks < 8; ++ks) {
      bf16x8 a = as_bf(qf[ks]);
#pragma unroll
      for (int nt = 0; nt < 4; ++nt) {
        u16x8 kfr = *(const u16x8*)(&K_lds[nt * 16 + l16][ks * 32 + g * 8]);
        s[nt] = __builtin_amdgcn_mfma_f32_16x16x32_bf16(a, as_bf(kfr), s[nt], 0, 0, 0);
      }
    }

    // online softmax; C-layout: col=lane&15, row=(lane>>4)*4+reg
    float mnew[4], alpha[4];
#pragma unroll
    for (int r = 0; r < 4; ++r) {
      float mx = fmaxf(fmaxf(s[0][r], s[1][r]), fmaxf(s[2][r], s[3][r]));
#pragma unroll
      for (int m = 8; m >= 1; m >>= 1) mx = fmaxf(mx, __shfl_xor(mx, m, 16));
      mnew[r] = fmaxf(m_i[r], mx);
      alpha[r] = __expf(m_i[r] - mnew[r]);
      m_i[r] = mnew[r];
    }
#pragma unroll
    for (int r = 0; r < 4; ++r) {
      float rs = 0.f;
#pragma unroll
      for (int nt = 0; nt < 4; ++nt) {
        float p = __expf(s[nt][r] - mnew[r]);
        s[nt][r] = p;
        rs += p;
      }
#pragma unroll
      for (int m = 8; m >= 1; m >>= 1) rs += __shfl_xor(rs, m, 16);
      l_i[r] = l_i[r] * alpha[r] + rs;
    }
    // P -> per-wave LDS (C-layout write, A-layout read)
#pragma unroll
    for (int nt = 0; nt < 4; ++nt)
#pragma unroll
      for (int r = 0; r < 4; ++r)
        P_lds[wid][g * 4 + r][nt * 16 + l16] = f2bf(s[nt][r]);
    // rescale O
#pragma unroll
    for (int nd = 0; nd < 16; ++nd)
#pragma unroll
      for (int r = 0; r < 4; ++r) Oacc[nd][r] *= alpha[r];
    // O += P @ V
#pragma unroll
    for (int kt = 0; kt < 2; ++kt) {
      u16x8 pa = *(const u16x8*)(&P_lds[wid][l16][kt * 32 + g * 8]);
      bf16x8 pab = as_bf(pa);
#pragma unroll
      for (int nd = 0; nd < 16; ++nd) {
        u16x8 vv = *(const u16x8*)(&V_lds[nd * 16 + l16][kt * 32 + g * 8]);
        Oacc[nd] = __builtin_amdgcn_mfma_f32_16x16x32_bf16(pab, as_bf(vv), Oacc[nd], 0, 0, 0);
      }
    }
  }

  // epilogue: out = O / l  (fp32)
  float inv_l[4];
#pragma unroll
  for (int r = 0; r < 4; ++r) inv_l[r] = 1.0f / l_i[r];
  float* outB = out + (size_t)(b * SEQ + q0 + wid * 16 + g * 4) * 256 + l16;
#pragma unroll
  for (int nd = 0; nd < 16; ++nd)
#pragma unroll
    for (int r = 0; r < 4; ++r)
      outB[(size_t)r * 256 + nd * 16] = Oacc[nd][r] * inv_l[r];
}

// ---------------------------------------------------------------------------
extern "C" void kernel_launch(void* const* d_in, const int* in_sizes, int n_in,
                              void* d_out, int out_size, void* d_ws, size_t ws_size,
                              hipStream_t stream) {
  (void)in_sizes; (void)n_in; (void)out_size; (void)ws_size;
  const float* conv_local  = (const float*)d_in[0];
  const float* conv_global = (const float*)d_in[1];
  const float* Wk = (const float*)d_in[2];
  const float* bk = (const float*)d_in[3];
  const float* Wq = (const float*)d_in[4];
  const float* bq = (const float*)d_in[5];
  const float* Wv = (const float*)d_in[6];
  const float* bv = (const float*)d_in[7];
  float* out = (float*)d_out;

  // ws layout (needs 24 MB + 384 KB):
  char* ws = (char*)d_ws;
  unsigned short* Qb = (unsigned short*)(ws);                     // 8 MB, Q*(1/16) bf16
  unsigned short* Kb = (unsigned short*)(ws + (8u << 20));        // 8 MB
  unsigned short* Vt = (unsigned short*)(ws + (16u << 20));       // 8 MB, [b][d][kv]
  unsigned short* Wt = (unsigned short*)(ws + (24u << 20));       // 384 KB, [3][n][k]

  wtrans_kernel<<<dim3(256, 3), 256, 0, stream>>>(Wq, Wk, Wv, Wt);
  proj_kernel<<<dim3(2, 128, 3), 256, 0, stream>>>(conv_global, conv_local, Wt,
                                                   bq, bk, bv, Qb, Kb, Vt);
  attn_kernel<<<dim3(64, 4), 256, 0, stream>>>(Qb, Kb, Vt, out);
}